// Round 11
// baseline (265.772 us; speedup 1.0000x reference)
//
#include <hip/hip_runtime.h>

// VQ straight-through: B=32, V=4096, D=64, K=512. N = 131072 rows.
// Outputs (flat, concatenated): z_q_st [N,D] f32, z_q [N,D] f32, indices [N] (as f32).
//
// Correctness contract (established R2/R3, passing): replicate numpy fp32 bitwise —
//  - sums of squares: numpy pairwise_sum scalar 8-accumulator order, products
//    rounded separately (no FMA contraction into the sum)
//  - z@e.T dots: sequential single-accumulator FMA chain over d=0..63 (BLAS)
//  - d2 = fl(fl(A - 2*dot) + C); argmin: global first-min (min value, tie -> min k)
//
// R16: R15 (196us) was clean (no spill, 92 VGPR, barrier-free k-loop) but sat
// at Occupancy 22.6% ~= 1 block/CU despite 35KB LDS / 92 VGPR allowing 2-4 —
// matching R13's forced-1-block number, while every 256-thread round (R5,R10)
// measured 44-51%. Hypothesis: 512-thread workgroups pack poorly on this
// part. Fix: same inner structure, re-grained to 256-thread blocks:
// ROWS=128, 4 waves, wave w owns codes {g*64 + 4j + w}, NG=8 groups.
// launch_bounds(256,2) (VGPR cap 256 — no R14 pressure trap). Everything
// else byte-for-byte R15: Mr=2 x Nr=16 acc tile, z dense from LDS, e from
// wave-uniform global (zero addr VALU, L1 broadcast), lex (value,index)
// cross-wave merge. Numerics op-for-op identical to R15 (passed).

#define VQ_N (32 * 4096)
#define VQ_D 64
#define VQ_K 512
#define ROWS 128     // rows per block
#define THREADS 256  // 4 waves
#define NG 8         // code-groups per wave
#define NR 16        // codes per wave per group (acc = MR*NR = 32)
#define MR 2         // rows per lane = ROWS / 64

// Rounding barrier: forbids FMA contraction / reassociation through x.
__device__ __forceinline__ float freeze(float x) {
  asm volatile("" : "+v"(x));
  return x;
}

// ---- kernel 1: C_k = np.sum(emb*emb, -1) in numpy fp32 order ----
__global__ __launch_bounds__(256) void vq_norms_kernel(
    const float* __restrict__ emb, float* __restrict__ nrm) {
  int k = blockIdx.x * blockDim.x + threadIdx.x;
  if (k < VQ_K) {
    const float* e = emb + k * VQ_D;
    float r0 = freeze(e[0] * e[0]), r1 = freeze(e[1] * e[1]);
    float r2 = freeze(e[2] * e[2]), r3 = freeze(e[3] * e[3]);
    float r4 = freeze(e[4] * e[4]), r5 = freeze(e[5] * e[5]);
    float r6 = freeze(e[6] * e[6]), r7 = freeze(e[7] * e[7]);
#pragma unroll
    for (int i = 8; i < VQ_D; i += 8) {
      r0 += freeze(e[i + 0] * e[i + 0]); r1 += freeze(e[i + 1] * e[i + 1]);
      r2 += freeze(e[i + 2] * e[i + 2]); r3 += freeze(e[i + 3] * e[i + 3]);
      r4 += freeze(e[i + 4] * e[i + 4]); r5 += freeze(e[i + 5] * e[i + 5]);
      r6 += freeze(e[i + 6] * e[i + 6]); r7 += freeze(e[i + 7] * e[i + 7]);
    }
    nrm[k] = ((r0 + r1) + (r2 + r3)) + ((r4 + r5) + (r6 + r7));
  }
}

// ---- kernel 2: main — 128 rows/block, 4 waves, Mr=2 x Nr=16 reg tile,
// ----            z from LDS (dense reads), e from uniform global ----
__global__ __launch_bounds__(THREADS, 2) void vq_main_kernel(
    const float* __restrict__ z_e, const float* __restrict__ emb,
    const float* __restrict__ nrm, float* __restrict__ out_st,
    float* __restrict__ out_q, float* __restrict__ out_idx) {
  __shared__ float4 z_lds[16][ROWS];  // 32 KB [d-chunk][row]
  __shared__ float A_lds[ROWS];       // 0.5 KB
  __shared__ float nrm_lds[VQ_K];     // 2 KB

  const int tid = threadIdx.x;
  const int lane = tid & 63;
  const int w = __builtin_amdgcn_readfirstlane(tid >> 6);  // wave id 0..3
  const size_t row0 = (size_t)blockIdx.x * ROWS;

  // Stage z tile (2048 float4, 8/thread, coalesced) + nrm (2 floats/thread).
  const float4* zg = (const float4*)(z_e + row0 * VQ_D);
#pragma unroll
  for (int t = 0; t < 8; ++t) {
    int i = t * THREADS + tid;
    z_lds[i & 15][i >> 4] = zg[i];
  }
  nrm_lds[tid] = nrm[tid];
  nrm_lds[THREADS + tid] = nrm[THREADS + tid];
  __syncthreads();

  // A-phase (verified since R10): numpy 8-accumulator order, acc j gets
  // d ≡ j mod 8; chunk pair (2c,2c+1) supplies d = 8c..8c+7.
  if (tid < ROWS) {
    float4 p0 = z_lds[0][tid], p1 = z_lds[1][tid];
    float r0 = freeze(p0.x * p0.x), r1 = freeze(p0.y * p0.y);
    float r2 = freeze(p0.z * p0.z), r3 = freeze(p0.w * p0.w);
    float r4 = freeze(p1.x * p1.x), r5 = freeze(p1.y * p1.y);
    float r6 = freeze(p1.z * p1.z), r7 = freeze(p1.w * p1.w);
#pragma unroll
    for (int c = 2; c < 16; c += 2) {
      float4 q0 = z_lds[c][tid], q1 = z_lds[c + 1][tid];
      r0 += freeze(q0.x * q0.x); r1 += freeze(q0.y * q0.y);
      r2 += freeze(q0.z * q0.z); r3 += freeze(q0.w * q0.w);
      r4 += freeze(q1.x * q1.x); r5 += freeze(q1.y * q1.y);
      r6 += freeze(q1.z * q1.z); r7 += freeze(q1.w * q1.w);
    }
    A_lds[tid] = ((r0 + r1) + (r2 + r3)) + ((r4 + r5) + (r6 + r7));
  }
  __syncthreads();

  float Ar[MR];
#pragma unroll
  for (int m = 0; m < MR; ++m) Ar[m] = A_lds[lane + 64 * m];

  float bestv[MR];
  int besti[MR];
#pragma unroll
  for (int m = 0; m < MR; ++m) { bestv[m] = 3.4e38f; besti[m] = 0; }

  const float4* e4 = (const float4*)emb;  // [K*16] float4, 128 KB (L2-hot)

  // k-loop: NO barriers, NO e staging. Wave w owns codes {g*64 + 4j + w}.
  for (int g = 0; g < NG; ++g) {
    float acc[MR][NR];
#pragma unroll
    for (int m = 0; m < MR; ++m)
#pragma unroll
      for (int j = 0; j < NR; ++j) acc[m][j] = 0.f;

#pragma unroll
    for (int c = 0; c < 16; ++c) {  // d = 4c..4c+3
      float4 zr[MR];
#pragma unroll
      for (int m = 0; m < MR; ++m) zr[m] = z_lds[c][lane + 64 * m];
#pragma unroll
      for (int j = 0; j < NR; ++j) {
        // Wave-uniform address: scalar base + broadcast transaction;
        // zero per-lane address VALU.
        float4 f = e4[(size_t)(g * 64 + 4 * j + w) * 16 + c];
#pragma unroll
        for (int m = 0; m < MR; ++m) {
          // Sequential single-accumulator chain, d ascending (BLAS order).
          acc[m][j] = fmaf(zr[m].x, f.x, acc[m][j]);
          acc[m][j] = fmaf(zr[m].y, f.y, acc[m][j]);
          acc[m][j] = fmaf(zr[m].z, f.z, acc[m][j]);
          acc[m][j] = fmaf(zr[m].w, f.w, acc[m][j]);
        }
      }
    }

    // d2 = fl(fl(A - 2*dot) + C); 2*dot exact => fmaf(-2,a,A) == fl(A-2a).
    // Within-wave k ascends over (g, j) -> strict < keeps wave-subset
    // first-min.
#pragma unroll
    for (int j = 0; j < NR; ++j) {
      const int k = g * 64 + 4 * j + w;
      const float C = nrm_lds[k];
#pragma unroll
      for (int m = 0; m < MR; ++m) {
        float tv = fmaf(-2.0f, acc[m][j], Ar[m]) + C;
        if (tv < bestv[m]) { bestv[m] = tv; besti[m] = k; }
      }
    }
  }

  // z_lds is dead from here; alias the cross-wave merge buffers into it.
  __syncthreads();  // all waves done reading z_lds
  float* zf = (float*)z_lds;
  float* sv = zf;                   // [4][128] values, 2 KB
  int* si = (int*)(zf + 4 * ROWS);  // [4][128] indices, 2 KB
#pragma unroll
  for (int m = 0; m < MR; ++m) {
    sv[w * ROWS + lane + 64 * m] = bestv[m];
    si[w * ROWS + lane + 64 * m] = besti[m];
  }
  __syncthreads();

  // Lexicographic (value, index) merge == np.argmin first-min (R11-verified).
  if (tid < ROWS) {
    float v = sv[tid];
    int b = si[tid];
#pragma unroll
    for (int q = 1; q < 4; ++q) {
      float vq = sv[q * ROWS + tid];
      int bq = si[q * ROWS + tid];
      if (vq < v || (vq == v && bq < b)) { v = vq; b = bq; }
    }
    ((int*)A_lds)[tid] = b;  // A_lds dead -> reuse as s_best (128 ints)
    out_idx[row0 + tid] = (float)b;
  }
  __syncthreads();

  // Coalesced output writes: 128 rows x 16 float4 per array = 2048 f4,
  // 256 threads -> 8 iterations.
  const int* s_best = (const int*)A_lds;
  const size_t base4 = row0 * 16;
  float4* o0 = (float4*)out_st;
  float4* o1 = (float4*)out_q;
#pragma unroll
  for (int t = 0; t < 8; ++t) {
    int i = t * THREADS + tid;
    int r = i >> 4, j = i & 15;
    float4 v = e4[s_best[r] * 16 + j];
    o0[base4 + i] = v;
    o1[base4 + i] = v;
  }
}

extern "C" void kernel_launch(void* const* d_in, const int* in_sizes, int n_in,
                              void* d_out, int out_size, void* d_ws,
                              size_t ws_size, hipStream_t stream) {
  const float* z_e = (const float*)d_in[0];  // [N, D] fp32
  const float* emb = (const float*)d_in[1];  // [K, D] fp32
  float* nrm = (float*)d_ws;                 // [K] fp32 scratch

  float* out_st = (float*)d_out;                 // [N, D]
  float* out_q = out_st + (size_t)VQ_N * VQ_D;   // [N, D]
  float* out_idx = out_q + (size_t)VQ_N * VQ_D;  // [N] as float

  vq_norms_kernel<<<(VQ_K + 255) / 256, 256, 0, stream>>>(emb, nrm);
  vq_main_kernel<<<VQ_N / ROWS, THREADS, 0, stream>>>(z_e, emb, nrm, out_st,
                                                      out_q, out_idx);
}

// Round 12
// 240.398 us; speedup vs baseline: 1.1056x; 1.1056x over previous
//
#include <hip/hip_runtime.h>

// VQ straight-through: B=32, V=4096, D=64, K=512. N = 131072 rows.
// Outputs (flat, concatenated): z_q_st [N,D] f32, z_q [N,D] f32, indices [N] (as f32).
//
// Correctness contract (established R2/R3, passing): replicate numpy fp32 bitwise —
//  - sums of squares: numpy pairwise_sum scalar 8-accumulator order, products
//    rounded separately (no FMA contraction into the sum)
//  - z@e.T dots: sequential single-accumulator FMA chain over d=0..63 (BLAS)
//  - d2 = fl(fl(A - 2*dot) + C); argmin: global first-min (min value, tie -> min k)
//
// R17: combine the two proven goods. Empirical law from R5..R16: occupancy
// tracks VGPR (40-44 -> 44-51%, 88-96 -> 21-23%) and duration tracks
// occupancy x instr count. R16 (Mr=2,Nr=16, 96 VGPR) halved e-loads vs R10
// but paid 2x residency. Fix: Mr=2 x Nr=4 — keeps the 8:1 FMA:load ratio
// (acc = 8, in-flight batch = 4 float4) at R10-class VGPR (~50-64).
// Addressing: group = 4 consecutive j at fixed (g,w) -> 64 loads fold to ONE
// base pointer + imm offsets (max 3312 < 4095), zero per-load address VALU.
// Else byte-for-byte R16 (passed): z dense from LDS, barrier-free k-loop,
// k = g*16 + 4j + w ascending within wave, lex (value,index) merge.

#define VQ_N (32 * 4096)
#define VQ_D 64
#define VQ_K 512
#define ROWS 128     // rows per block
#define THREADS 256  // 4 waves
#define NG 32        // code-groups per wave
#define NR 4         // codes per wave per group (acc = MR*NR = 8)
#define MR 2         // rows per lane = ROWS / 64

// Rounding barrier: forbids FMA contraction / reassociation through x.
__device__ __forceinline__ float freeze(float x) {
  asm volatile("" : "+v"(x));
  return x;
}

// ---- kernel 1: C_k = np.sum(emb*emb, -1) in numpy fp32 order ----
__global__ __launch_bounds__(256) void vq_norms_kernel(
    const float* __restrict__ emb, float* __restrict__ nrm) {
  int k = blockIdx.x * blockDim.x + threadIdx.x;
  if (k < VQ_K) {
    const float* e = emb + k * VQ_D;
    float r0 = freeze(e[0] * e[0]), r1 = freeze(e[1] * e[1]);
    float r2 = freeze(e[2] * e[2]), r3 = freeze(e[3] * e[3]);
    float r4 = freeze(e[4] * e[4]), r5 = freeze(e[5] * e[5]);
    float r6 = freeze(e[6] * e[6]), r7 = freeze(e[7] * e[7]);
#pragma unroll
    for (int i = 8; i < VQ_D; i += 8) {
      r0 += freeze(e[i + 0] * e[i + 0]); r1 += freeze(e[i + 1] * e[i + 1]);
      r2 += freeze(e[i + 2] * e[i + 2]); r3 += freeze(e[i + 3] * e[i + 3]);
      r4 += freeze(e[i + 4] * e[i + 4]); r5 += freeze(e[i + 5] * e[i + 5]);
      r6 += freeze(e[i + 6] * e[i + 6]); r7 += freeze(e[i + 7] * e[i + 7]);
    }
    nrm[k] = ((r0 + r1) + (r2 + r3)) + ((r4 + r5) + (r6 + r7));
  }
}

// ---- kernel 2: main — 128 rows/block, 4 waves, Mr=2 x Nr=4 reg tile,
// ----            z from LDS (dense reads), e from uniform global ----
__global__ __launch_bounds__(THREADS, 2) void vq_main_kernel(
    const float* __restrict__ z_e, const float* __restrict__ emb,
    const float* __restrict__ nrm, float* __restrict__ out_st,
    float* __restrict__ out_q, float* __restrict__ out_idx) {
  __shared__ float4 z_lds[16][ROWS];  // 32 KB [d-chunk][row]
  __shared__ float A_lds[ROWS];       // 0.5 KB
  __shared__ float nrm_lds[VQ_K];     // 2 KB

  const int tid = threadIdx.x;
  const int lane = tid & 63;
  const int w = __builtin_amdgcn_readfirstlane(tid >> 6);  // wave id 0..3
  const size_t row0 = (size_t)blockIdx.x * ROWS;

  // Stage z tile (2048 float4, 8/thread, coalesced) + nrm (2 floats/thread).
  const float4* zg = (const float4*)(z_e + row0 * VQ_D);
#pragma unroll
  for (int t = 0; t < 8; ++t) {
    int i = t * THREADS + tid;
    z_lds[i & 15][i >> 4] = zg[i];
  }
  nrm_lds[tid] = nrm[tid];
  nrm_lds[THREADS + tid] = nrm[THREADS + tid];
  __syncthreads();

  // A-phase (verified since R10): numpy 8-accumulator order, acc j gets
  // d ≡ j mod 8; chunk pair (2c,2c+1) supplies d = 8c..8c+7.
  if (tid < ROWS) {
    float4 p0 = z_lds[0][tid], p1 = z_lds[1][tid];
    float r0 = freeze(p0.x * p0.x), r1 = freeze(p0.y * p0.y);
    float r2 = freeze(p0.z * p0.z), r3 = freeze(p0.w * p0.w);
    float r4 = freeze(p1.x * p1.x), r5 = freeze(p1.y * p1.y);
    float r6 = freeze(p1.z * p1.z), r7 = freeze(p1.w * p1.w);
#pragma unroll
    for (int c = 2; c < 16; c += 2) {
      float4 q0 = z_lds[c][tid], q1 = z_lds[c + 1][tid];
      r0 += freeze(q0.x * q0.x); r1 += freeze(q0.y * q0.y);
      r2 += freeze(q0.z * q0.z); r3 += freeze(q0.w * q0.w);
      r4 += freeze(q1.x * q1.x); r5 += freeze(q1.y * q1.y);
      r6 += freeze(q1.z * q1.z); r7 += freeze(q1.w * q1.w);
    }
    A_lds[tid] = ((r0 + r1) + (r2 + r3)) + ((r4 + r5) + (r6 + r7));
  }
  __syncthreads();

  float Ar[MR];
#pragma unroll
  for (int m = 0; m < MR; ++m) Ar[m] = A_lds[lane + 64 * m];

  float bestv[MR];
  int besti[MR];
#pragma unroll
  for (int m = 0; m < MR; ++m) { bestv[m] = 3.4e38f; besti[m] = 0; }

  const float4* e4 = (const float4*)emb;  // [K*16] float4, 128 KB (L2-hot)

  // k-loop: NO barriers, NO e staging. Wave w owns codes {g*16 + 4j + w}.
  // Group base pointer: all 64 loads of a group use imm offsets
  // (1024*j + 16*c bytes, max 3312 < 4095) -> zero per-load address VALU.
  for (int g = 0; g < NG; ++g) {
    const float4* ep = e4 + (size_t)(g * 16 + w) * 16;
    float acc[MR][NR];
#pragma unroll
    for (int m = 0; m < MR; ++m)
#pragma unroll
      for (int j = 0; j < NR; ++j) acc[m][j] = 0.f;

#pragma unroll
    for (int c = 0; c < 16; ++c) {  // d = 4c..4c+3
      float4 zr[MR];
#pragma unroll
      for (int m = 0; m < MR; ++m) zr[m] = z_lds[c][lane + 64 * m];
#pragma unroll
      for (int j = 0; j < NR; ++j) {
        float4 f = ep[64 * j + c];  // uniform addr, imm offset
#pragma unroll
        for (int m = 0; m < MR; ++m) {
          // Sequential single-accumulator chain, d ascending (BLAS order).
          acc[m][j] = fmaf(zr[m].x, f.x, acc[m][j]);
          acc[m][j] = fmaf(zr[m].y, f.y, acc[m][j]);
          acc[m][j] = fmaf(zr[m].z, f.z, acc[m][j]);
          acc[m][j] = fmaf(zr[m].w, f.w, acc[m][j]);
        }
      }
    }

    // d2 = fl(fl(A - 2*dot) + C); 2*dot exact => fmaf(-2,a,A) == fl(A-2a).
    // Within-wave k ascends over (g, j) -> strict < keeps wave-subset
    // first-min.
#pragma unroll
    for (int j = 0; j < NR; ++j) {
      const int k = g * 16 + 4 * j + w;
      const float C = nrm_lds[k];
#pragma unroll
      for (int m = 0; m < MR; ++m) {
        float tv = fmaf(-2.0f, acc[m][j], Ar[m]) + C;
        if (tv < bestv[m]) { bestv[m] = tv; besti[m] = k; }
      }
    }
  }

  // z_lds is dead from here; alias the cross-wave merge buffers into it.
  __syncthreads();  // all waves done reading z_lds
  float* zf = (float*)z_lds;
  float* sv = zf;                   // [4][128] values, 2 KB
  int* si = (int*)(zf + 4 * ROWS);  // [4][128] indices, 2 KB
#pragma unroll
  for (int m = 0; m < MR; ++m) {
    sv[w * ROWS + lane + 64 * m] = bestv[m];
    si[w * ROWS + lane + 64 * m] = besti[m];
  }
  __syncthreads();

  // Lexicographic (value, index) merge == np.argmin first-min (R11-verified).
  if (tid < ROWS) {
    float v = sv[tid];
    int b = si[tid];
#pragma unroll
    for (int q = 1; q < 4; ++q) {
      float vq = sv[q * ROWS + tid];
      int bq = si[q * ROWS + tid];
      if (vq < v || (vq == v && bq < b)) { v = vq; b = bq; }
    }
    ((int*)A_lds)[tid] = b;  // A_lds dead -> reuse as s_best (128 ints)
    out_idx[row0 + tid] = (float)b;
  }
  __syncthreads();

  // Coalesced output writes: 128 rows x 16 float4 per array = 2048 f4,
  // 256 threads -> 8 iterations.
  const int* s_best = (const int*)A_lds;
  const size_t base4 = row0 * 16;
  float4* o0 = (float4*)out_st;
  float4* o1 = (float4*)out_q;
#pragma unroll
  for (int t = 0; t < 8; ++t) {
    int i = t * THREADS + tid;
    int r = i >> 4, j = i & 15;
    float4 v = e4[s_best[r] * 16 + j];
    o0[base4 + i] = v;
    o1[base4 + i] = v;
  }
}

extern "C" void kernel_launch(void* const* d_in, const int* in_sizes, int n_in,
                              void* d_out, int out_size, void* d_ws,
                              size_t ws_size, hipStream_t stream) {
  const float* z_e = (const float*)d_in[0];  // [N, D] fp32
  const float* emb = (const float*)d_in[1];  // [K, D] fp32
  float* nrm = (float*)d_ws;                 // [K] fp32 scratch

  float* out_st = (float*)d_out;                 // [N, D]
  float* out_q = out_st + (size_t)VQ_N * VQ_D;   // [N, D]
  float* out_idx = out_q + (size_t)VQ_N * VQ_D;  // [N] as float

  vq_norms_kernel<<<(VQ_K + 255) / 256, 256, 0, stream>>>(emb, nrm);
  vq_main_kernel<<<VQ_N / ROWS, THREADS, 0, stream>>>(z_e, emb, nrm, out_st,
                                                      out_q, out_idx);
}